// Round 6
// baseline (261.259 us; speedup 1.0000x reference)
//
#include <hip/hip_runtime.h>

// loss = a*sum(pn^2) + 2*sum(z)*sum(pn) + sum(z^2)*(N - a)
//   z = (margin - p) on positives, pn = p on negatives, a = #positives.
// Streaming reduction: 268 MB read, one scalar out.
//
// R10 theory: R7 proved L3-hit service runs CONCURRENTLY with HBM streaming
// (1.7 TB/s each, lockstep-coupled by the per-iteration pred/lab interleave).
// R8 proved pure-HBM nt streaming gives ~4.1 TB/s. R9 proved it's not
// latency-bound (MLP null in both regimes). This version uses BOTH paths in
// parallel, decoupled by an address-space partition:
//   region 1 = first ~31% of both arrays (~84 MB), NORMAL loads ->
//              stays L3-resident (R7 evidence), served from Infinity Cache;
//   region 2 = rest (~184 MB), NT loads -> pure HBM stream, no L3 pollution;
//   blocks 0..b1-1 grid-stride region 1, blocks b1.. grid-stride region 2.
// Predict: FETCH ~262 -> ~184 MB, reduce ~65-75 -> ~48-55 us, total ~235 us.
// If FETCH drops but dur doesn't: common request-rate cap -> R8 was roofline.

constexpr float MARGIN = 1.0f;

#define BLOCK 256
#define MAX_BLOCKS 2048
#define SLOT_STRIDE 8            // floats per block slot (32 B)

typedef float v4f __attribute__((ext_vector_type(4)));
typedef int   v4i __attribute__((ext_vector_type(4)));

__device__ __forceinline__ float wave_reduce(float v) {
    #pragma unroll
    for (int off = 32; off > 0; off >>= 1) v += __shfl_down(v, off, 64);
    return v;
}

struct Acc { float a, sz, sz2, sp, sp2; };

__device__ __forceinline__ void acc1(float px, int lx, Acc& s) {
    float ispos = (lx == 1) ? 1.0f : 0.0f;
    float z  = ispos * (MARGIN - px);
    s.a   += ispos;
    s.sz  += z;
    s.sz2  = fmaf(z, z, s.sz2);
    float pn = (lx == 1) ? 0.0f : px;
    s.sp  += pn;
    s.sp2  = fmaf(pn, pn, s.sp2);
}

__device__ __forceinline__ void acc4(const v4f& p, const v4i& l, Acc& s) {
    acc1(p[0], l[0], s);
    acc1(p[1], l[1], s);
    acc1(p[2], l[2], s);
    acc1(p[3], l[3], s);
}

__global__ __launch_bounds__(BLOCK, 8) void hinge2_reduce(
    const float* __restrict__ pred, const int* __restrict__ lab,
    float* __restrict__ ws, int nvec, int split, int b1)
{
    const v4f* p4 = reinterpret_cast<const v4f*>(pred);
    const v4i* l4 = reinterpret_cast<const v4i*>(lab);

    Acc s = {0.f, 0.f, 0.f, 0.f, 0.f};
    const int tid = threadIdx.x;

    if (blockIdx.x < b1) {
        // ---- region 1: [0, split), NORMAL loads (L3-resident) ----
        const int step = b1 * (BLOCK * 2);
        int i = blockIdx.x * (BLOCK * 2) + tid;
        while (i + BLOCK < split) {
            v4f p0 = p4[i];
            v4f p1 = p4[i + BLOCK];
            v4i l0 = l4[i];
            v4i l1 = l4[i + BLOCK];
            acc4(p0, l0, s);
            acc4(p1, l1, s);
            i += step;
        }
        if (i < split) {
            v4f p = p4[i];
            v4i l = l4[i];
            acc4(p, l, s);
        }
    } else {
        // ---- region 2: [split, nvec), NT loads (pure HBM stream) ----
        const int b2   = gridDim.x - b1;
        const int step = b2 * (BLOCK * 2);
        int i = split + (blockIdx.x - b1) * (BLOCK * 2) + tid;
        while (i + BLOCK < nvec) {
            v4f p0 = __builtin_nontemporal_load(p4 + i);
            v4f p1 = __builtin_nontemporal_load(p4 + i + BLOCK);
            v4i l0 = __builtin_nontemporal_load(l4 + i);
            v4i l1 = __builtin_nontemporal_load(l4 + i + BLOCK);
            acc4(p0, l0, s);
            acc4(p1, l1, s);
            i += step;
        }
        if (i < nvec) {
            v4f p = __builtin_nontemporal_load(p4 + i);
            v4i l = __builtin_nontemporal_load(l4 + i);
            acc4(p, l, s);
        }
    }

    // block reduction
    s.a   = wave_reduce(s.a);
    s.sz  = wave_reduce(s.sz);
    s.sz2 = wave_reduce(s.sz2);
    s.sp  = wave_reduce(s.sp);
    s.sp2 = wave_reduce(s.sp2);

    __shared__ float sdata[4][5];
    int lane = tid & 63;
    int wid  = tid >> 6;
    if (lane == 0) {
        sdata[wid][0] = s.a;
        sdata[wid][1] = s.sz;
        sdata[wid][2] = s.sz2;
        sdata[wid][3] = s.sp;
        sdata[wid][4] = s.sp2;
    }
    __syncthreads();

    if (tid == 0) {
        float t0 = 0.f, t1 = 0.f, t2 = 0.f, t3 = 0.f, t4 = 0.f;
        #pragma unroll
        for (int w = 0; w < 4; ++w) {
            t0 += sdata[w][0];
            t1 += sdata[w][1];
            t2 += sdata[w][2];
            t3 += sdata[w][3];
            t4 += sdata[w][4];
        }
        float* slot = ws + (size_t)blockIdx.x * SLOT_STRIDE;
        slot[0] = t0;  // plain stores to a private slot: no init required
        slot[1] = t1;
        slot[2] = t2;
        slot[3] = t3;
        slot[4] = t4;
    }
}

__global__ __launch_bounds__(BLOCK) void hinge2_final(
    const float* __restrict__ ws,
    const float* __restrict__ pred, const int* __restrict__ lab,
    float* __restrict__ out, int n, int tail_start, int nslots)
{
    int t = threadIdx.x;
    double a = 0., sz = 0., sz2 = 0., sp = 0., sp2 = 0.;
    for (int b = t; b < nslots; b += BLOCK) {
        const float* slot = ws + (size_t)b * SLOT_STRIDE;
        a   += (double)slot[0];
        sz  += (double)slot[1];
        sz2 += (double)slot[2];
        sp  += (double)slot[3];
        sp2 += (double)slot[4];
    }
    #pragma unroll
    for (int off = 32; off > 0; off >>= 1) {
        a   += __shfl_down(a,   off, 64);
        sz  += __shfl_down(sz,  off, 64);
        sz2 += __shfl_down(sz2, off, 64);
        sp  += __shfl_down(sp,  off, 64);
        sp2 += __shfl_down(sp2, off, 64);
    }

    __shared__ double sdata[4][5];
    int lane = t & 63, wid = t >> 6;
    if (lane == 0) {
        sdata[wid][0] = a;  sdata[wid][1] = sz; sdata[wid][2] = sz2;
        sdata[wid][3] = sp; sdata[wid][4] = sp2;
    }
    __syncthreads();

    if (t == 0) {
        double A = 0, SZ = 0, SZ2 = 0, SP = 0, SP2 = 0;
        #pragma unroll
        for (int w = 0; w < 4; ++w) {
            A   += sdata[w][0];
            SZ  += sdata[w][1];
            SZ2 += sdata[w][2];
            SP  += sdata[w][3];
            SP2 += sdata[w][4];
        }
        for (int i = tail_start; i < n; ++i) {
            float p = pred[i];
            if (lab[i] == 1) {
                double z = (double)MARGIN - (double)p;
                A += 1.0; SZ += z; SZ2 += z * z;
            } else {
                SP += (double)p; SP2 += (double)p * (double)p;
            }
        }
        double loss = A * SP2 + 2.0 * SZ * SP + SZ2 * ((double)n - A);
        out[0] = (float)loss;
    }
}

extern "C" void kernel_launch(void* const* d_in, const int* in_sizes, int n_in,
                              void* d_out, int out_size, void* d_ws, size_t ws_size,
                              hipStream_t stream)
{
    const float* pred = (const float*)d_in[0];
    const int*   lab  = (const int*)d_in[1];
    float*       out  = (float*)d_out;
    float*       ws   = (float*)d_ws;

    int n    = in_sizes[0];
    int nvec = n >> 2;                        // float4 / int4 groups
    int tail = nvec << 2;

    // one private slot per block; plain stores -> no memset needed
    int blocks = MAX_BLOCKS;
    int needed = (nvec + BLOCK * 2 - 1) / (BLOCK * 2);
    if (blocks > needed) blocks = needed;
    size_t max_slots = ws_size / (SLOT_STRIDE * sizeof(float));
    if (max_slots > 0 && (size_t)blocks > max_slots) blocks = (int)max_slots;
    if (blocks < 1) blocks = 1;

    // L3/HBM split: region 1 = 5/16 of groups (normal loads, L3-resident),
    // region 2 = 11/16 (nt loads, HBM). b1 = 5/16 of blocks. At N=2^25,
    // blocks=2048: b1=640, split=2621440 -> both regions = exactly 8 full
    // iterations/block, no tails. Cap region-1 bytes at ~192 MB for L3 fit.
    int b1    = (blocks * 5) / 16;
    int split = 0;
    if (b1 > 0) {
        long long sp = ((long long)nvec * 5) / 16;
        long long cap = 192LL * 1024 * 1024 / 32;   // groups: 32 B per group
        if (sp > cap) sp = cap;
        split = (int)(sp & ~((long long)(BLOCK * 2 - 1)));
        if (split <= 0) { b1 = 0; split = 0; }
    }

    hinge2_reduce<<<blocks, BLOCK, 0, stream>>>(pred, lab, ws, nvec, split, b1);
    hinge2_final<<<1, BLOCK, 0, stream>>>(ws, pred, lab, out, n, tail, blocks);
}